// Round 1
// baseline (95.378 us; speedup 1.0000x reference)
//
#include <hip/hip_runtime.h>
#include <hip/hip_bf16.h>
#include <math.h>

// TokenCompressor: B=8, N=16384, C=128, BLOCK=32, STRIDE=16 -> nb=1023
// Decomposition: chunks c of 16 tokens; A = x.view(8192, 2048) (contiguous!)
//   P[m, 0:256]  = chunk[m] @ W1[0:2048]    (first-half contribution)
//   P[m, 256:512]= chunk[m] @ W1[2048:4096] (second-half contribution)
//   h[j] = gelu(P[j,0:256] + P[j+1,256:512] + b1 + posflat@W1)
//   out[j] = h[j] @ W2 + b2
// Everything matmul-shaped runs as bf16 MFMA (16x16x32) with fp32 accum.

typedef __attribute__((ext_vector_type(8))) short short8;
typedef __attribute__((ext_vector_type(4))) float f4;

#define OFF_BT   0u                         // 512x2048 bf16 = 2 MB
#define OFF_W2T  (2u << 20)                 // 128x256 bf16 = 64 KB
#define OFF_PART ((2u << 20) + (64u << 10)) // 64x256 f32 = 64 KB
#define OFF_BIAS ((2u << 20) + (128u << 10))// 256 f32
#define OFF_P    (4u << 20)                 // 8192x512 bf16 = 8 MB

static __device__ __forceinline__ unsigned short f2bf(float f) {
  union { float f; unsigned u; } v; v.f = f;
  return (unsigned short)((v.u + 0x7FFFu + ((v.u >> 16) & 1u)) >> 16);
}
static __device__ __forceinline__ float bf2f(unsigned short h) {
  union { unsigned u; float f; } v; v.u = ((unsigned)h) << 16;
  return v.f;
}

// ---------------- k0: W2 (256x128 f32) -> W2t (128x256 bf16, transposed) ----
__global__ __launch_bounds__(256) void k_w2t(const float* __restrict__ W2,
                                             unsigned short* __restrict__ W2t) {
  int n = blockIdx.x;   // 0..127
  int t = threadIdx.x;  // 0..255 (k index)
  W2t[n * 256 + t] = f2bf(W2[t * 128 + n]);
}

// ---------------- k1: W1 -> Bt (512x2048 bf16, n-major) + bias partials -----
// wg = (h, kt, nt): h selects W1 half (rows 2048h..), kt 64-row band, nt 64-col band.
__global__ __launch_bounds__(256) void k_prep(const float* __restrict__ W1,
                                              const float* __restrict__ pos,
                                              unsigned short* __restrict__ Bt,
                                              float* __restrict__ part) {
  __shared__ float T[64][65];  // +1 pad
  const int w = blockIdx.x;
  const int h = w >> 7, rem = w & 127, kt = rem >> 2, nt = rem & 3;
  const int krow0 = h * 2048 + kt * 64, col0 = nt * 64;
  const int t = threadIdx.x;
  const int lr = t >> 2, lc = (t & 3) * 16;
  const float* src = W1 + (size_t)(krow0 + lr) * 256 + col0 + lc;
#pragma unroll
  for (int i = 0; i < 4; ++i) {
    f4 v = *(const f4*)(src + i * 4);
#pragma unroll
    for (int q = 0; q < 4; ++q) T[lr][lc + i * 4 + q] = v[q];
  }
  __syncthreads();
  // bias partial: threads 0..63 each own one n column of this tile
  if (t < 64) {
    float s = 0.f;
#pragma unroll 8
    for (int k = 0; k < 64; ++k) s += T[k][t] * pos[krow0 + k];
    part[(h * 32 + kt) * 256 + col0 + t] = s;
  }
  // transposed bf16 write: Bt[n'][k'] with n' = 256h + col0 + nl
  const int nl = t >> 2, kc = (t & 3) * 16;
  short8 o0, o1;
#pragma unroll
  for (int i = 0; i < 8; ++i) o0[i] = (short)f2bf(T[kc + i][nl]);
#pragma unroll
  for (int i = 0; i < 8; ++i) o1[i] = (short)f2bf(T[kc + 8 + i][nl]);
  unsigned short* dst = Bt + (size_t)(256 * h + col0 + nl) * 2048 + kt * 64 + kc;
  *(short8*)dst = o0;
  *(short8*)(dst + 8) = o1;
}

// ---------------- k1b: reduce bias partials ---------------------------------
__global__ __launch_bounds__(256) void k_bias(const float* __restrict__ b1,
                                              const float* __restrict__ part,
                                              float* __restrict__ bias) {
  int n = threadIdx.x;
  float s = b1[n];
#pragma unroll 8
  for (int g = 0; g < 64; ++g) s += part[g * 256 + n];
  bias[n] = s;
}

// ---------------- k2: GEMM1  P(8192x512 bf16) = A(f32) @ Bt^T ---------------
// 128x128 tile, BK=64, 4 waves x (64x64). A reg-staged f32->bf16, B bf16 copy.
// LDS rows are 64 bf16 = 128 B; XOR swizzle c16 ^= (row&7) for conflict-free
// frag reads (G4).
__global__ __launch_bounds__(256) void k_gemm(const float* __restrict__ X,
                                              const unsigned short* __restrict__ Bt,
                                              unsigned short* __restrict__ P) {
  __shared__ unsigned short As[2][128 * 64];
  __shared__ unsigned short Bs[2][128 * 64];
  const int wgid = blockIdx.x;
  const int mt = wgid & 63, nt = wgid >> 6;  // mt fastest -> XCD keeps M-band
  const int m0 = mt * 128, n0 = nt * 128;
  const int t = threadIdx.x;
  const int wid = t >> 6, lane = t & 63;
  const int wm = (wid >> 1) * 64, wn = (wid & 1) * 64;
  const int sr = t >> 1;              // staging row 0..127
  const int scA = (t & 1) * 32;       // col offset (elements)
  const int cbase = (t & 1) * 4;      // 16B-chunk base
  const float* Ag = X + (size_t)(m0 + sr) * 2048 + scA;
  const unsigned short* Bg = Bt + (size_t)(n0 + sr) * 2048 + scA;

  f4 acc[4][4];
#pragma unroll
  for (int i = 0; i < 4; ++i)
#pragma unroll
    for (int j = 0; j < 4; ++j) acc[i][j] = f4{0.f, 0.f, 0.f, 0.f};

  f4 aldr[8];
  short8 bldr[4];

#define LOADK(K0)                                                         \
  do {                                                                    \
    const float* ap = Ag + (K0);                                          \
    _Pragma("unroll") for (int i = 0; i < 8; ++i)                         \
        aldr[i] = *(const f4*)(ap + i * 4);                               \
    const unsigned short* bp = Bg + (K0);                                 \
    _Pragma("unroll") for (int i = 0; i < 4; ++i)                         \
        bldr[i] = *(const short8*)(bp + i * 8);                           \
  } while (0)

#define STOREK(BUF)                                                       \
  do {                                                                    \
    _Pragma("unroll") for (int i = 0; i < 4; ++i) {                       \
      short8 pk;                                                          \
      _Pragma("unroll") for (int q = 0; q < 8; ++q)                       \
          pk[q] = (short)f2bf(aldr[i * 2 + (q >> 2)][q & 3]);             \
      const int c = (cbase + i) ^ (sr & 7);                               \
      *(short8*)&As[BUF][sr * 64 + c * 8] = pk;                           \
      *(short8*)&Bs[BUF][sr * 64 + c * 8] = bldr[i];                      \
    }                                                                     \
  } while (0)

  LOADK(0);
  STOREK(0);
  __syncthreads();

  for (int kt = 0; kt < 32; ++kt) {
    const int cur = kt & 1;
    if (kt + 1 < 32) LOADK((kt + 1) * 64);
#pragma unroll
    for (int ks = 0; ks < 2; ++ks) {
      short8 af[4], bfr[4];
      const int cc = ks * 4 + (lane >> 4);
#pragma unroll
      for (int f = 0; f < 4; ++f) {
        const int ra = wm + f * 16 + (lane & 15);
        af[f] = *(const short8*)&As[cur][ra * 64 + ((cc ^ (ra & 7)) << 3)];
        const int rb = wn + f * 16 + (lane & 15);
        bfr[f] = *(const short8*)&Bs[cur][rb * 64 + ((cc ^ (rb & 7)) << 3)];
      }
#pragma unroll
      for (int i = 0; i < 4; ++i)
#pragma unroll
        for (int j = 0; j < 4; ++j)
          acc[i][j] = __builtin_amdgcn_mfma_f32_16x16x32_bf16(af[i], bfr[j],
                                                              acc[i][j], 0, 0, 0);
    }
    if (kt + 1 < 32) STOREK((kt + 1) & 1);
    __syncthreads();
  }
#undef LOADK
#undef STOREK

  // epilogue: P[m][n'] bf16.  C/D layout: col=lane&15, row=(lane>>4)*4+reg
  const int mb = m0 + wm, nb = n0 + wn;
#pragma unroll
  for (int i = 0; i < 4; ++i)
#pragma unroll
    for (int j = 0; j < 4; ++j) {
      const int row0 = mb + i * 16 + ((lane >> 4) << 2);
      const int col = nb + j * 16 + (lane & 15);
#pragma unroll
      for (int r = 0; r < 4; ++r)
        P[(size_t)(row0 + r) * 512 + col] = f2bf(acc[i][j][r]);
    }
}

// ---------------- k3: combine: h=gelu(P0+P1+bias); out = h@W2 + b2 ----------
// wg = (b, jt): 32 block-rows. LDS: W2s 128x256 bf16 (64KB) + Hs 32x256 (16KB)
__global__ __launch_bounds__(256) void k_comb(const unsigned short* __restrict__ P,
                                              const unsigned short* __restrict__ W2t,
                                              const float* __restrict__ bias,
                                              const float* __restrict__ b2,
                                              float* __restrict__ out) {
  __shared__ unsigned short W2s[128 * 256];
  __shared__ unsigned short Hs[32 * 256];
  const int wg = blockIdx.x;
  const int b = wg >> 5, jt = wg & 31;
  const int j0 = jt * 32;
  const int t = threadIdx.x;

  {  // stage W2t (rows 512B; swizzle slot ^= row&7)
    const int row = t >> 1, halfc = (t & 1) * 128;
    const unsigned short* src = W2t + row * 256 + halfc;
    const int cb = halfc >> 3;  // 0 or 16
#pragma unroll
    for (int i = 0; i < 16; ++i) {
      short8 v = *(const short8*)(src + i * 8);
      const int c = (cb + i) ^ (row & 7);
      *(short8*)&W2s[row * 256 + c * 8] = v;
    }
  }
  {  // h rows: thread = (row r, 32-col segment)
    const int r = t >> 3, seg = t & 7;
    const int j = j0 + r;
    const size_t m = (size_t)b * 1024 + j;
    const size_t mp1 = (j < 1023) ? m + 1 : m;  // clamp (masked later)
    const unsigned short* p0 = P + m * 512 + seg * 32;
    const unsigned short* p1 = P + mp1 * 512 + 256 + seg * 32;
    const float* bs = bias + seg * 32;
    const int cb = seg * 4;
#pragma unroll
    for (int i = 0; i < 4; ++i) {
      short8 v0 = *(const short8*)(p0 + i * 8);
      short8 v1 = *(const short8*)(p1 + i * 8);
      short8 pk;
#pragma unroll
      for (int q = 0; q < 8; ++q) {
        float f = bf2f((unsigned short)v0[q]) + bf2f((unsigned short)v1[q]) +
                  bs[i * 8 + q];
        float g = 0.5f * f * (1.f + erff(f * 0.70710678118f));
        pk[q] = (short)f2bf(g);
      }
      const int c = (cb + i) ^ (r & 7);
      *(short8*)&Hs[r * 256 + c * 8] = pk;
    }
  }
  __syncthreads();

  const int wid = t >> 6, lane = t & 63;
  f4 acc[2][2];
#pragma unroll
  for (int i = 0; i < 2; ++i)
#pragma unroll
    for (int j = 0; j < 2; ++j) acc[i][j] = f4{0.f, 0.f, 0.f, 0.f};

#pragma unroll
  for (int ks = 0; ks < 8; ++ks) {
    short8 af[2], bfr[2];
    const int cc = ks * 4 + (lane >> 4);
#pragma unroll
    for (int f = 0; f < 2; ++f) {
      const int ra = f * 16 + (lane & 15);
      af[f] = *(const short8*)&Hs[ra * 256 + ((cc ^ (ra & 7)) << 3)];
      const int rb = wid * 32 + f * 16 + (lane & 15);
      bfr[f] = *(const short8*)&W2s[rb * 256 + ((cc ^ (rb & 7)) << 3)];
    }
#pragma unroll
    for (int i = 0; i < 2; ++i)
#pragma unroll
      for (int j = 0; j < 2; ++j)
        acc[i][j] = __builtin_amdgcn_mfma_f32_16x16x32_bf16(af[i], bfr[j],
                                                            acc[i][j], 0, 0, 0);
  }
  // epilogue: out[b, j, n] f32 (+b2), mask j<1023
#pragma unroll
  for (int i = 0; i < 2; ++i)
#pragma unroll
    for (int j = 0; j < 2; ++j) {
      const int row0 = i * 16 + ((lane >> 4) << 2);
      const int col = wid * 32 + j * 16 + (lane & 15);
      const float bb = b2[col];
#pragma unroll
      for (int r = 0; r < 4; ++r) {
        const int jj = j0 + row0 + r;
        if (jj < 1023)
          out[((size_t)b * 1023 + jj) * 128 + col] = acc[i][j][r] + bb;
      }
    }
}

extern "C" void kernel_launch(void* const* d_in, const int* in_sizes, int n_in,
                              void* d_out, int out_size, void* d_ws, size_t ws_size,
                              hipStream_t stream) {
  const float* x   = (const float*)d_in[0];
  const float* pos = (const float*)d_in[1];
  const float* W1  = (const float*)d_in[2];
  const float* b1  = (const float*)d_in[3];
  const float* W2  = (const float*)d_in[4];
  const float* b2  = (const float*)d_in[5];
  float* out = (float*)d_out;
  char* ws = (char*)d_ws;
  unsigned short* Bt  = (unsigned short*)(ws + OFF_BT);
  unsigned short* W2t = (unsigned short*)(ws + OFF_W2T);
  float* part         = (float*)(ws + OFF_PART);
  float* bias         = (float*)(ws + OFF_BIAS);
  unsigned short* P   = (unsigned short*)(ws + OFF_P);

  k_w2t<<<128, 256, 0, stream>>>(W2, W2t);
  k_prep<<<256, 256, 0, stream>>>(W1, pos, Bt, part);
  k_bias<<<1, 256, 0, stream>>>(b1, part, bias);
  k_gemm<<<256, 256, 0, stream>>>(x, Bt, P);
  k_comb<<<256, 256, 0, stream>>>(P, W2t, bias, b2, out);
}

// Round 2
// 70.680 us; speedup vs baseline: 1.3494x; 1.3494x over previous
//
#include <hip/hip_runtime.h>
#include <hip/hip_bf16.h>
#include <math.h>

// TokenCompressor: B=8, N=16384, C=128, BLOCK=32, STRIDE=16 -> nb=1023
// Decomposition: chunks c of 16 tokens; A = x.view(8192, 2048) (contiguous!)
//   P[m, 0:256]  = chunk[m] @ W1[0:2048]    (first-half contribution)
//   P[m, 256:512]= chunk[m] @ W1[2048:4096] (second-half contribution)
//   h[j] = gelu(P[j,0:256] + P[j+1,256:512] + b1 + posflat@W1)
//   out[j] = h[j] @ W2 + b2
// R2: k_gemm re-tiled 128x128 -> 64x64 (1024 wgs, 4 blocks/CU) to fix the
// 9.5% occupancy / 7.8% MfmaUtil latency starvation seen in R1 counters.

typedef __attribute__((ext_vector_type(8))) short short8;
typedef __attribute__((ext_vector_type(4))) float f4;

#define OFF_BT   0u                         // 512x2048 bf16 = 2 MB
#define OFF_W2T  (2u << 20)                 // 128x256 bf16 = 64 KB
#define OFF_PART ((2u << 20) + (64u << 10)) // 64x256 f32 = 64 KB
#define OFF_BIAS ((2u << 20) + (128u << 10))// 256 f32
#define OFF_P    (4u << 20)                 // 8192x512 bf16 = 8 MB

static __device__ __forceinline__ unsigned short f2bf(float f) {
  union { float f; unsigned u; } v; v.f = f;
  return (unsigned short)((v.u + 0x7FFFu + ((v.u >> 16) & 1u)) >> 16);
}
static __device__ __forceinline__ float bf2f(unsigned short h) {
  union { unsigned u; float f; } v; v.u = ((unsigned)h) << 16;
  return v.f;
}

// ---- k_prep: blocks 0..255: W1 -> Bt (512x2048 bf16, n-major) + bias parts
//              blocks 256..383: W2 (256x128 f32) -> W2t (128x256 bf16, T)
__global__ __launch_bounds__(256) void k_prep(const float* __restrict__ W1,
                                              const float* __restrict__ pos,
                                              const float* __restrict__ W2,
                                              unsigned short* __restrict__ Bt,
                                              unsigned short* __restrict__ W2t,
                                              float* __restrict__ part) {
  __shared__ float T[64][65];  // +1 pad
  const int w = blockIdx.x;
  const int t = threadIdx.x;
  if (w >= 256) {  // W2 transpose role
    const int n = w - 256;  // 0..127
    W2t[n * 256 + t] = f2bf(W2[t * 128 + n]);
    return;
  }
  const int h = w >> 7, rem = w & 127, kt = rem >> 2, nt = rem & 3;
  const int krow0 = h * 2048 + kt * 64, col0 = nt * 64;
  const int lr = t >> 2, lc = (t & 3) * 16;
  const float* src = W1 + (size_t)(krow0 + lr) * 256 + col0 + lc;
#pragma unroll
  for (int i = 0; i < 4; ++i) {
    f4 v = *(const f4*)(src + i * 4);
#pragma unroll
    for (int q = 0; q < 4; ++q) T[lr][lc + i * 4 + q] = v[q];
  }
  __syncthreads();
  if (t < 64) {
    float s = 0.f;
#pragma unroll 8
    for (int k = 0; k < 64; ++k) s += T[k][t] * pos[krow0 + k];
    part[(h * 32 + kt) * 256 + col0 + t] = s;
  }
  const int nl = t >> 2, kc = (t & 3) * 16;
  short8 o0, o1;
#pragma unroll
  for (int i = 0; i < 8; ++i) o0[i] = (short)f2bf(T[kc + i][nl]);
#pragma unroll
  for (int i = 0; i < 8; ++i) o1[i] = (short)f2bf(T[kc + 8 + i][nl]);
  unsigned short* dst = Bt + (size_t)(256 * h + col0 + nl) * 2048 + kt * 64 + kc;
  *(short8*)dst = o0;
  *(short8*)(dst + 8) = o1;
}

// ---- k_bias: reduce bias partials --------------------------------------
__global__ __launch_bounds__(256) void k_bias(const float* __restrict__ b1,
                                              const float* __restrict__ part,
                                              float* __restrict__ bias) {
  int n = threadIdx.x;
  float s = b1[n];
#pragma unroll 8
  for (int g = 0; g < 64; ++g) s += part[g * 256 + n];
  bias[n] = s;
}

// ---- k_gemm: P(8192x512 bf16) = A(f32) @ Bt^T --------------------------
// 64x64 tile, BK=64, 1024 wgs (4 blocks/CU), 4 waves x (32x32).
// A reg-staged f32->bf16; XOR chunk swizzle c ^= (row&7) (G4, conflict-free).
// XCD bijective swizzle, nt fastest inside chunk -> A-band L2 reuse.
__global__ __launch_bounds__(256, 4) void k_gemm(const float* __restrict__ X,
                                                 const unsigned short* __restrict__ Bt,
                                                 unsigned short* __restrict__ P) {
  __shared__ unsigned short As[2][64 * 64];
  __shared__ unsigned short Bs[2][64 * 64];
  const int orig = blockIdx.x;
  const int wg = (orig & 7) * 128 + (orig >> 3);  // 1024 % 8 == 0 -> bijective
  const int mt = wg >> 3, nt = wg & 7;
  const int m0 = mt * 64, n0 = nt * 64;
  const int t = threadIdx.x;
  const int wid = t >> 6, lane = t & 63;
  const int wm = (wid >> 1) * 32, wn = (wid & 1) * 32;
  const int sr = t >> 2;           // staging row 0..63
  const int sc = (t & 3) * 16;     // element col offset
  const int cb = (t & 3) * 2;      // 16B-chunk base (2 chunks/thread)
  const float* Ag = X + (size_t)(m0 + sr) * 2048 + sc;
  const unsigned short* Bg = Bt + (size_t)(n0 + sr) * 2048 + sc;

  f4 acc[2][2];
#pragma unroll
  for (int i = 0; i < 2; ++i)
#pragma unroll
    for (int j = 0; j < 2; ++j) acc[i][j] = f4{0.f, 0.f, 0.f, 0.f};

  f4 aldr[4];
  short8 bldr[2];

#define LOADK(K0)                                                         \
  do {                                                                    \
    const float* ap = Ag + (K0);                                          \
    _Pragma("unroll") for (int i = 0; i < 4; ++i)                         \
        aldr[i] = *(const f4*)(ap + i * 4);                               \
    const unsigned short* bp = Bg + (K0);                                 \
    bldr[0] = *(const short8*)(bp);                                       \
    bldr[1] = *(const short8*)(bp + 8);                                   \
  } while (0)

#define STOREK(BUF)                                                       \
  do {                                                                    \
    _Pragma("unroll") for (int i = 0; i < 2; ++i) {                       \
      short8 pk;                                                          \
      _Pragma("unroll") for (int q = 0; q < 8; ++q)                       \
          pk[q] = (short)f2bf(aldr[i * 2 + (q >> 2)][q & 3]);             \
      const int c = (cb + i) ^ (sr & 7);                                  \
      *(short8*)&As[BUF][sr * 64 + c * 8] = pk;                           \
      *(short8*)&Bs[BUF][sr * 64 + c * 8] = bldr[i];                      \
    }                                                                     \
  } while (0)

  LOADK(0);
  STOREK(0);
  __syncthreads();

  for (int kt = 0; kt < 32; ++kt) {
    const int cur = kt & 1;
    if (kt + 1 < 32) LOADK((kt + 1) * 64);
#pragma unroll
    for (int ks = 0; ks < 2; ++ks) {
      short8 af[2], bfr[2];
      const int cc = ks * 4 + (lane >> 4);
#pragma unroll
      for (int f = 0; f < 2; ++f) {
        const int ra = wm + f * 16 + (lane & 15);
        af[f] = *(const short8*)&As[cur][ra * 64 + ((cc ^ (ra & 7)) << 3)];
        const int rb = wn + f * 16 + (lane & 15);
        bfr[f] = *(const short8*)&Bs[cur][rb * 64 + ((cc ^ (rb & 7)) << 3)];
      }
#pragma unroll
      for (int i = 0; i < 2; ++i)
#pragma unroll
        for (int j = 0; j < 2; ++j)
          acc[i][j] = __builtin_amdgcn_mfma_f32_16x16x32_bf16(af[i], bfr[j],
                                                              acc[i][j], 0, 0, 0);
    }
    if (kt + 1 < 32) STOREK((kt + 1) & 1);
    __syncthreads();
  }
#undef LOADK
#undef STOREK

  // epilogue: P[m][n'] bf16.  C/D layout: col=lane&15, row=(lane>>4)*4+reg
  const int mb = m0 + wm, nb = n0 + wn;
#pragma unroll
  for (int i = 0; i < 2; ++i)
#pragma unroll
    for (int j = 0; j < 2; ++j) {
      const int row0 = mb + i * 16 + ((lane >> 4) << 2);
      const int col = nb + j * 16 + (lane & 15);
#pragma unroll
      for (int r = 0; r < 4; ++r)
        P[(size_t)(row0 + r) * 512 + col] = f2bf(acc[i][j][r]);
    }
}

// ---- k_comb: h=gelu(P0+P1+bias); out = h@W2 + b2 -----------------------
__global__ __launch_bounds__(256) void k_comb(const unsigned short* __restrict__ P,
                                              const unsigned short* __restrict__ W2t,
                                              const float* __restrict__ bias,
                                              const float* __restrict__ b2,
                                              float* __restrict__ out) {
  __shared__ unsigned short W2s[128 * 256];
  __shared__ unsigned short Hs[32 * 256];
  const int wg = blockIdx.x;
  const int b = wg >> 5, jt = wg & 31;
  const int j0 = jt * 32;
  const int t = threadIdx.x;

  {  // stage W2t (rows 512B; swizzle slot ^= row&7)
    const int row = t >> 1, halfc = (t & 1) * 128;
    const unsigned short* src = W2t + row * 256 + halfc;
    const int cbw = halfc >> 3;  // 0 or 16
#pragma unroll
    for (int i = 0; i < 16; ++i) {
      short8 v = *(const short8*)(src + i * 8);
      const int c = (cbw + i) ^ (row & 7);
      *(short8*)&W2s[row * 256 + c * 8] = v;
    }
  }
  {  // h rows: thread = (row r, 32-col segment)
    const int r = t >> 3, seg = t & 7;
    const int j = j0 + r;
    const size_t m = (size_t)b * 1024 + j;
    const size_t mp1 = (j < 1023) ? m + 1 : m;  // clamp (masked later)
    const unsigned short* p0 = P + m * 512 + seg * 32;
    const unsigned short* p1 = P + mp1 * 512 + 256 + seg * 32;
    const float* bs = bias + seg * 32;
    const int cbh = seg * 4;
#pragma unroll
    for (int i = 0; i < 4; ++i) {
      short8 v0 = *(const short8*)(p0 + i * 8);
      short8 v1 = *(const short8*)(p1 + i * 8);
      short8 pk;
#pragma unroll
      for (int q = 0; q < 8; ++q) {
        float f = bf2f((unsigned short)v0[q]) + bf2f((unsigned short)v1[q]) +
                  bs[i * 8 + q];
        float g = 0.5f * f * (1.f + erff(f * 0.70710678118f));
        pk[q] = (short)f2bf(g);
      }
      const int c = (cbh + i) ^ (r & 7);
      *(short8*)&Hs[r * 256 + c * 8] = pk;
    }
  }
  __syncthreads();

  const int wid = t >> 6, lane = t & 63;
  f4 acc[2][2];
#pragma unroll
  for (int i = 0; i < 2; ++i)
#pragma unroll
    for (int j = 0; j < 2; ++j) acc[i][j] = f4{0.f, 0.f, 0.f, 0.f};

#pragma unroll
  for (int ks = 0; ks < 8; ++ks) {
    short8 af[2], bfr[2];
    const int cc = ks * 4 + (lane >> 4);
#pragma unroll
    for (int f = 0; f < 2; ++f) {
      const int ra = f * 16 + (lane & 15);
      af[f] = *(const short8*)&Hs[ra * 256 + ((cc ^ (ra & 7)) << 3)];
      const int rb = wid * 32 + f * 16 + (lane & 15);
      bfr[f] = *(const short8*)&W2s[rb * 256 + ((cc ^ (rb & 7)) << 3)];
    }
#pragma unroll
    for (int i = 0; i < 2; ++i)
#pragma unroll
      for (int j = 0; j < 2; ++j)
        acc[i][j] = __builtin_amdgcn_mfma_f32_16x16x32_bf16(af[i], bfr[j],
                                                            acc[i][j], 0, 0, 0);
  }
#pragma unroll
  for (int i = 0; i < 2; ++i)
#pragma unroll
    for (int j = 0; j < 2; ++j) {
      const int row0 = i * 16 + ((lane >> 4) << 2);
      const int col = wid * 32 + j * 16 + (lane & 15);
      const float bb = b2[col];
#pragma unroll
      for (int r = 0; r < 4; ++r) {
        const int jj = j0 + row0 + r;
        if (jj < 1023)
          out[((size_t)b * 1023 + jj) * 128 + col] = acc[i][j][r] + bb;
      }
    }
}

extern "C" void kernel_launch(void* const* d_in, const int* in_sizes, int n_in,
                              void* d_out, int out_size, void* d_ws, size_t ws_size,
                              hipStream_t stream) {
  const float* x   = (const float*)d_in[0];
  const float* pos = (const float*)d_in[1];
  const float* W1  = (const float*)d_in[2];
  const float* b1  = (const float*)d_in[3];
  const float* W2  = (const float*)d_in[4];
  const float* b2  = (const float*)d_in[5];
  float* out = (float*)d_out;
  char* ws = (char*)d_ws;
  unsigned short* Bt  = (unsigned short*)(ws + OFF_BT);
  unsigned short* W2t = (unsigned short*)(ws + OFF_W2T);
  float* part         = (float*)(ws + OFF_PART);
  float* bias         = (float*)(ws + OFF_BIAS);
  unsigned short* P   = (unsigned short*)(ws + OFF_P);

  k_prep<<<384, 256, 0, stream>>>(W1, pos, W2, Bt, W2t, part);
  k_bias<<<1, 256, 0, stream>>>(b1, part, bias);
  k_gemm<<<1024, 256, 0, stream>>>(x, Bt, P);
  k_comb<<<256, 256, 0, stream>>>(P, W2t, bias, b2, out);
}

// Round 3
// 69.217 us; speedup vs baseline: 1.3779x; 1.0211x over previous
//
#include <hip/hip_runtime.h>
#include <hip/hip_bf16.h>
#include <math.h>

// TokenCompressor: B=8, N=16384, C=128, BLOCK=32, STRIDE=16 -> nb=1023
// Decomposition: chunks c of 16 tokens; A = x.view(8192, 2048) (contiguous!)
//   P[m, 0:256]  = chunk[m] @ W1[0:2048]
//   P[m, 256:512]= chunk[m] @ W1[2048:4096]
//   h[j] = gelu(P[j,0:256] + P[j+1,256:512] + b1 + posflat@W1)
//   out[j] = h[j] @ W2 + b2
// R3: k_gemm -> 128x128 tile, split-K=2 (512 wgs, 2/CU), B staged via
// global_load_lds with pre-swizzled source, A double-reg pipelined (2-ahead).
// R2 evidence: occupancy tripled but MfmaUtil ~9.5% -> latency + cache-BW
// bound; this raises MFMA/barrier 4x and cuts cache traffic ~45%.

typedef __attribute__((ext_vector_type(8))) short short8;
typedef __attribute__((ext_vector_type(4))) float f4;

#define OFF_BT   0u                          // 512x2048 bf16 = 2 MB
#define OFF_W2T  (2u << 20)                  // 128x256 bf16 = 64 KB
#define OFF_PART ((2u << 20) + (64u << 10))  // 64x256 f32 = 64 KB
#define OFF_BIAS ((2u << 20) + (128u << 10)) // 256 f32
#define OFF_P    (4u << 20)                  // 2 x (8192x512) bf16 = 16 MB

static __device__ __forceinline__ unsigned short f2bf(float f) {
  union { float f; unsigned u; } v; v.f = f;
  return (unsigned short)((v.u + 0x7FFFu + ((v.u >> 16) & 1u)) >> 16);
}
static __device__ __forceinline__ float bf2f(unsigned short h) {
  union { unsigned u; float f; } v; v.u = ((unsigned)h) << 16;
  return v.f;
}
static __device__ __forceinline__ void gload_lds16(const void* g, void* l) {
  __builtin_amdgcn_global_load_lds(
      (const __attribute__((address_space(1))) void*)g,
      (__attribute__((address_space(3))) void*)l, 16, 0, 0);
}

// ---- k_prep: blocks 0..255: W1 -> Bt (512x2048 bf16, n-major) + bias parts
//              blocks 256..383: W2 (256x128 f32) -> W2t (128x256 bf16, T)
__global__ __launch_bounds__(256) void k_prep(const float* __restrict__ W1,
                                              const float* __restrict__ pos,
                                              const float* __restrict__ W2,
                                              unsigned short* __restrict__ Bt,
                                              unsigned short* __restrict__ W2t,
                                              float* __restrict__ part) {
  __shared__ float T[64][65];
  const int w = blockIdx.x;
  const int t = threadIdx.x;
  if (w >= 256) {
    const int n = w - 256;
    W2t[n * 256 + t] = f2bf(W2[t * 128 + n]);
    return;
  }
  const int h = w >> 7, rem = w & 127, kt = rem >> 2, nt = rem & 3;
  const int krow0 = h * 2048 + kt * 64, col0 = nt * 64;
  const int lr = t >> 2, lc = (t & 3) * 16;
  const float* src = W1 + (size_t)(krow0 + lr) * 256 + col0 + lc;
#pragma unroll
  for (int i = 0; i < 4; ++i) {
    f4 v = *(const f4*)(src + i * 4);
#pragma unroll
    for (int q = 0; q < 4; ++q) T[lr][lc + i * 4 + q] = v[q];
  }
  __syncthreads();
  if (t < 64) {
    float s = 0.f;
#pragma unroll 8
    for (int k = 0; k < 64; ++k) s += T[k][t] * pos[krow0 + k];
    part[(h * 32 + kt) * 256 + col0 + t] = s;
  }
  const int nl = t >> 2, kc = (t & 3) * 16;
  short8 o0, o1;
#pragma unroll
  for (int i = 0; i < 8; ++i) o0[i] = (short)f2bf(T[kc + i][nl]);
#pragma unroll
  for (int i = 0; i < 8; ++i) o1[i] = (short)f2bf(T[kc + 8 + i][nl]);
  unsigned short* dst = Bt + (size_t)(256 * h + col0 + nl) * 2048 + kt * 64 + kc;
  *(short8*)dst = o0;
  *(short8*)(dst + 8) = o1;
}

// ---- k_bias ------------------------------------------------------------
__global__ __launch_bounds__(256) void k_bias(const float* __restrict__ b1,
                                              const float* __restrict__ part,
                                              float* __restrict__ bias) {
  int n = threadIdx.x;
  float s = b1[n];
#pragma unroll 8
  for (int g = 0; g < 64; ++g) s += part[g * 256 + n];
  bias[n] = s;
}

// ---- k_gemm: Ppart[ks] (8192x512 bf16) = A(f32)[:,ks*1024:+1024] @ Bt^T ----
// 128x128 tile, BK=64, 16 kt. 4 waves x (64x64). 2 blocks/CU.
// B: global_load_lds (pre-swizzled source, linear LDS dest, swizzled read).
// A: reg-staged f32->bf16, 2-ahead load pipeline.
__global__ __launch_bounds__(256, 2) void k_gemm(const float* __restrict__ X,
                                                 const unsigned short* __restrict__ Bt,
                                                 unsigned short* __restrict__ P) {
  __shared__ unsigned short As[2][128 * 64];
  __shared__ unsigned short Bs[2][128 * 64];
  const int orig = blockIdx.x;
  const int wg = (orig & 7) * 64 + (orig >> 3);  // 512 % 8 == 0 -> bijective
  const int mt = wg >> 3, r3 = wg & 7;
  const int ks_split = r3 >> 2, nt = r3 & 3;
  const int m0 = mt * 128, n0 = nt * 128;
  const int k0 = ks_split * 1024;
  const int t = threadIdx.x;
  const int wid = t >> 6, lane = t & 63;
  const int wm = (wid >> 1) * 64, wn = (wid & 1) * 64;
  const int sr = t >> 1;           // A staging row 0..127
  const int sc = (t & 1) * 32;     // A f32 col offset
  const int cb = (t & 1) * 4;      // A 16B-chunk base
  const float* Ag = X + (size_t)(m0 + sr) * 2048 + k0 + sc;

  f4 acc[4][4];
#pragma unroll
  for (int i = 0; i < 4; ++i)
#pragma unroll
    for (int j = 0; j < 4; ++j) acc[i][j] = f4{0.f, 0.f, 0.f, 0.f};

  f4 ra0[8], ra1[8];

#define A_LOAD(RS, KT)                                                    \
  do {                                                                    \
    const float* ap = Ag + (KT) * 64;                                     \
    _Pragma("unroll") for (int i = 0; i < 8; ++i)                         \
        RS[i] = *(const f4*)(ap + i * 4);                                 \
  } while (0)

#define A_STORE(RS, BUF)                                                  \
  do {                                                                    \
    _Pragma("unroll") for (int i = 0; i < 4; ++i) {                       \
      short8 pk;                                                          \
      _Pragma("unroll") for (int q = 0; q < 8; ++q)                       \
          pk[q] = (short)f2bf(RS[i * 2 + (q >> 2)][q & 3]);               \
      const int c = (cb + i) ^ (sr & 7);                                  \
      *(short8*)&As[BUF][sr * 64 + c * 8] = pk;                           \
    }                                                                     \
  } while (0)

  // B DMA: LDS slot (r,c) must hold global chunk c^(r&7); thread t of issue
  // ii covers slot r=ii*32+(t>>3), c=t&7; per-wave uniform LDS base.
#define B_ISSUE(BUF, KT)                                                  \
  do {                                                                    \
    const size_t kofs = (size_t)k0 + (size_t)(KT) * 64;                   \
    _Pragma("unroll") for (int ii = 0; ii < 4; ++ii) {                    \
      const int rr = ii * 32 + (t >> 3);                                  \
      const int ch = (t & 7) ^ (rr & 7);                                  \
      const unsigned short* gsrc =                                        \
          Bt + (size_t)(n0 + rr) * 2048 + kofs + ch * 8;                  \
      char* ldst = ((char*)&Bs[BUF][0]) + ii * 4096 + wid * 1024;         \
      gload_lds16(gsrc, ldst);                                            \
    }                                                                     \
  } while (0)

#define COMPUTE(BUF)                                                      \
  do {                                                                    \
    _Pragma("unroll") for (int ks = 0; ks < 2; ++ks) {                    \
      short8 af[4], bfv[4];                                               \
      const int cc = ks * 4 + (lane >> 4);                                \
      _Pragma("unroll") for (int f = 0; f < 4; ++f) {                     \
        const int rా = 0;                                                 \
        (void)rా;                                                         \
        const int raA = wm + f * 16 + (lane & 15);                        \
        af[f] = *(const short8*)&As[BUF][raA * 64 + ((cc ^ (raA & 7)) << 3)]; \
        const int rbB = wn + f * 16 + (lane & 15);                        \
        bfv[f] = *(const short8*)&Bs[BUF][rbB * 64 + ((cc ^ (rbB & 7)) << 3)]; \
      }                                                                   \
      _Pragma("unroll") for (int i2 = 0; i2 < 4; ++i2)                    \
          _Pragma("unroll") for (int j2 = 0; j2 < 4; ++j2)                \
          acc[i2][j2] = __builtin_amdgcn_mfma_f32_16x16x32_bf16(          \
              af[i2], bfv[j2], acc[i2][j2], 0, 0, 0);                     \
    }                                                                     \
  } while (0)

  // prologue
  A_LOAD(ra0, 0);
  B_ISSUE(0, 0);
  A_STORE(ra0, 0);
  A_LOAD(ra1, 1);
  __syncthreads();

#pragma unroll
  for (int kt = 0; kt < 16; ++kt) {
    const int cur = kt & 1;
    if (kt + 1 < 16) B_ISSUE(cur ^ 1, kt + 1);
    COMPUTE(cur);
    if (kt + 1 < 16) {
      if (cur) A_STORE(ra0, cur ^ 1);
      else     A_STORE(ra1, cur ^ 1);
    }
    if (kt + 2 < 16) {
      if (cur) A_LOAD(ra1, kt + 2);
      else     A_LOAD(ra0, kt + 2);
    }
    __syncthreads();
  }
#undef A_LOAD
#undef A_STORE
#undef B_ISSUE
#undef COMPUTE

  // epilogue: partial write. C/D layout: col=lane&15, row=(lane>>4)*4+reg
  unsigned short* Pp = P + (size_t)ks_split * (8192 * 512);
  const int mb = m0 + wm, nb = n0 + wn;
#pragma unroll
  for (int i = 0; i < 4; ++i)
#pragma unroll
    for (int j = 0; j < 4; ++j) {
      const int row0 = mb + i * 16 + ((lane >> 4) << 2);
      const int col = nb + j * 16 + (lane & 15);
#pragma unroll
      for (int r = 0; r < 4; ++r)
        Pp[(size_t)(row0 + r) * 512 + col] = f2bf(acc[i][j][r]);
    }
}

// ---- k_comb: h=gelu(Pa0+Pb0+Pa1+Pb1+bias); out = h@W2 + b2 -------------
__global__ __launch_bounds__(256) void k_comb(const unsigned short* __restrict__ P,
                                              const unsigned short* __restrict__ W2t,
                                              const float* __restrict__ bias,
                                              const float* __restrict__ b2,
                                              float* __restrict__ out) {
  __shared__ unsigned short W2s[128 * 256];
  __shared__ unsigned short Hs[32 * 256];
  const unsigned short* Pa = P;
  const unsigned short* Pb = P + (size_t)8192 * 512;
  const int wg = blockIdx.x;
  const int b = wg >> 5, jt = wg & 31;
  const int j0 = jt * 32;
  const int t = threadIdx.x;

  {  // stage W2t
    const int row = t >> 1, halfc = (t & 1) * 128;
    const unsigned short* src = W2t + row * 256 + halfc;
    const int cbw = halfc >> 3;
#pragma unroll
    for (int i = 0; i < 16; ++i) {
      short8 v = *(const short8*)(src + i * 8);
      const int c = (cbw + i) ^ (row & 7);
      *(short8*)&W2s[row * 256 + c * 8] = v;
    }
  }
  {  // h rows
    const int r = t >> 3, seg = t & 7;
    const int j = j0 + r;
    const size_t m = (size_t)b * 1024 + j;
    const size_t mp1 = (j < 1023) ? m + 1 : m;
    const unsigned short* p0a = Pa + m * 512 + seg * 32;
    const unsigned short* p0b = Pb + m * 512 + seg * 32;
    const unsigned short* p1a = Pa + mp1 * 512 + 256 + seg * 32;
    const unsigned short* p1b = Pb + mp1 * 512 + 256 + seg * 32;
    const float* bs = bias + seg * 32;
    const int cbh = seg * 4;
#pragma unroll
    for (int i = 0; i < 4; ++i) {
      short8 v0a = *(const short8*)(p0a + i * 8);
      short8 v0b = *(const short8*)(p0b + i * 8);
      short8 v1a = *(const short8*)(p1a + i * 8);
      short8 v1b = *(const short8*)(p1b + i * 8);
      short8 pk;
#pragma unroll
      for (int q = 0; q < 8; ++q) {
        float f = bf2f((unsigned short)v0a[q]) + bf2f((unsigned short)v0b[q]) +
                  bf2f((unsigned short)v1a[q]) + bf2f((unsigned short)v1b[q]) +
                  bs[i * 8 + q];
        float g = 0.5f * f * (1.f + erff(f * 0.70710678118f));
        pk[q] = (short)f2bf(g);
      }
      const int c = (cbh + i) ^ (r & 7);
      *(short8*)&Hs[r * 256 + c * 8] = pk;
    }
  }
  __syncthreads();

  const int wid = t >> 6, lane = t & 63;
  f4 acc[2][2];
#pragma unroll
  for (int i = 0; i < 2; ++i)
#pragma unroll
    for (int j = 0; j < 2; ++j) acc[i][j] = f4{0.f, 0.f, 0.f, 0.f};

#pragma unroll
  for (int ks = 0; ks < 8; ++ks) {
    short8 af[2], bfr[2];
    const int cc = ks * 4 + (lane >> 4);
#pragma unroll
    for (int f = 0; f < 2; ++f) {
      const int ra = f * 16 + (lane & 15);
      af[f] = *(const short8*)&Hs[ra * 256 + ((cc ^ (ra & 7)) << 3)];
      const int rb = wid * 32 + f * 16 + (lane & 15);
      bfr[f] = *(const short8*)&W2s[rb * 256 + ((cc ^ (rb & 7)) << 3)];
    }
#pragma unroll
    for (int i = 0; i < 2; ++i)
#pragma unroll
      for (int j = 0; j < 2; ++j)
        acc[i][j] = __builtin_amdgcn_mfma_f32_16x16x32_bf16(af[i], bfr[j],
                                                            acc[i][j], 0, 0, 0);
  }
#pragma unroll
  for (int i = 0; i < 2; ++i)
#pragma unroll
    for (int j = 0; j < 2; ++j) {
      const int row0 = i * 16 + ((lane >> 4) << 2);
      const int col = wid * 32 + j * 16 + (lane & 15);
      const float bb = b2[col];
#pragma unroll
      for (int r = 0; r < 4; ++r) {
        const int jj = j0 + row0 + r;
        if (jj < 1023)
          out[((size_t)b * 1023 + jj) * 128 + col] = acc[i][j][r] + bb;
      }
    }
}

extern "C" void kernel_launch(void* const* d_in, const int* in_sizes, int n_in,
                              void* d_out, int out_size, void* d_ws, size_t ws_size,
                              hipStream_t stream) {
  const float* x   = (const float*)d_in[0];
  const float* pos = (const float*)d_in[1];
  const float* W1  = (const float*)d_in[2];
  const float* b1  = (const float*)d_in[3];
  const float* W2  = (const float*)d_in[4];
  const float* b2  = (const float*)d_in[5];
  float* out = (float*)d_out;
  char* ws = (char*)d_ws;
  unsigned short* Bt  = (unsigned short*)(ws + OFF_BT);
  unsigned short* W2t = (unsigned short*)(ws + OFF_W2T);
  float* part         = (float*)(ws + OFF_PART);
  float* bias         = (float*)(ws + OFF_BIAS);
  unsigned short* P   = (unsigned short*)(ws + OFF_P);

  k_prep<<<384, 256, 0, stream>>>(W1, pos, W2, Bt, W2t, part);
  k_bias<<<1, 256, 0, stream>>>(b1, part, bias);
  k_gemm<<<512, 256, 0, stream>>>(x, Bt, P);
  k_comb<<<256, 256, 0, stream>>>(P, W2t, bias, b2, out);
}